// Round 5
// baseline (297.198 us; speedup 1.0000x reference)
//
#include <hip/hip_runtime.h>

// CubicHermite2d: B=32, N=1024, axes are arange(N) => uniform knots, dx=1.
//
// out[b,k,p] = Hx(h0y*row_{Iy} + h2y*row_{Iy+1})(xs[p])
//            + h1y*(S[b,Iy+1,p]-S[b,Iy,p]) + h3y*(S[b,Iy+2,p]-S[b,Iy+1,p])
//
// R1: Hermite_x linear in row => stage ONE combined row (3 taps/output).
// R2: 4 batches/block (XCD-pinned) + nt-stores -> FETCH ~= compulsory.
// R4: b128 batch-interleaved gather (conflicts 7.4M->3.1M) - still ~90us.
// R5: zero-barrier wave-independent, occupancy 36->67% - still ~92us.
//     => All variants share ONE invariant: 384MB logical reads (3 rows per
//     (b,k)) served by L3 (FETCH only ~150MB, L2 working set 16MB >> 4MB,
//     row re-users scattered in time). 384MB / ~4.5TB/s L3 ~= 85us = the
//     observed floor. L3-READ-BW-BOUND.
// R6 (this round): Iy-SORTED k ORDER -> L2-LOCAL ROW REUSE.
//     Pre-kernel rank-sorts ys (1024 elems, brute force, ~3us) into perm
//     (d_ws). Main kernel processes k = perm[f>>3]: resident blocks per XCD
//     span ~220 consecutive sorted positions ~= 230-row sliding window x
//     4 pinned batches x 4KB ~= 3.6MB < 4MB L2. Rows enter L2 once, serve
//     all ~3 consumers from L2; L3 reads drop 384->~140MB.
//     Also revert nt-stores -> normal stores (common factor of the three
//     88-92us regressions vs the <=79.7us normal-store baseline).

#define NGRID 1024
#define BATCH 32
#define KB    4      // batches per block = waves per block (BATCH = 8 XCDs * KB)

// ---- pre-kernel: perm = argsort(ys) via brute-force rank (N=1024) ----
__global__ __launch_bounds__(64) void build_perm(
    const float* __restrict__ ys, int* __restrict__ perm)
{
    const int k = (int)(blockIdx.x * 64 + threadIdx.x);  // 16 blocks x 64
    const float v = ys[k];
    int r = 0;
    #pragma unroll 4
    for (int j = 0; j < NGRID; ++j) {
        const float u = ys[j];
        r += (u < v) || (u == v && j < k);   // stable, total order -> bijection
    }
    perm[r] = k;
}

__global__ __launch_bounds__(256) void hermite2d_fused(
    const float* __restrict__ signal,   // [B, N, N]
    const float* __restrict__ xs,       // [N]
    const float* __restrict__ ys,       // [N]
    const int*   __restrict__ perm,     // [N] Iy-sorted k order
    float* __restrict__ out)            // [B, N(k), N(p)]
{
    const unsigned f = blockIdx.x;      // 0..8191
    const int xcd  = (int)(f & 7u);     // XCD-pinned batch group
    const int k    = perm[f >> 3];      // sorted position -> y-query index
    const int w    = threadIdx.x >> 6;  // wave id 0..3 -> batch b0+w
    const int lane = threadIdx.x & 63;
    const int b    = xcd * KB + w;

    __shared__ float crow[KB][NGRID];   // 4 KB per wave, wave-private

    // --- y-direction coefficients (uniform per block) ---
    const float qy = ys[k];
    int Iy = (int)floorf(qy);
    if (Iy < 0) Iy = 0;
    if (Iy > NGRID - 3) Iy = NGRID - 3;
    const float ty  = qy - (float)Iy;
    const float ty2 = ty * ty;
    const float ty3 = ty2 * ty;
    const float h0y = 1.0f - 3.0f * ty2 + 2.0f * ty3;
    const float h1y = ty - 2.0f * ty2 + ty3;
    const float h2y = 3.0f * ty2 - 2.0f * ty3;
    const float h3y = ty3 - ty2;

    const float4* src4 =
        (const float4*)(signal + ((size_t)b * NGRID + (size_t)Iy) * NGRID);

    // --- phase 1: per chunk c, lane handles float4 slot c*64+lane ---
    // LDS write slot = c*64+lane -> bank group lane%8: conflict-free.
    float colp[KB][4];
    #pragma unroll
    for (int c = 0; c < 4; ++c) {
        const int s = c * 64 + lane;
        const float4 r0 = src4[s];
        const float4 r1 = src4[s + NGRID / 4];
        const float4 r2 = src4[s + NGRID / 2];

        float4 cc;
        cc.x = h0y * r0.x + h2y * r1.x;
        cc.y = h0y * r0.y + h2y * r1.y;
        cc.z = h0y * r0.z + h2y * r1.z;
        cc.w = h0y * r0.w + h2y * r1.w;
        ((float4*)crow[w])[s] = cc;

        colp[c][0] = h1y * (r1.x - r0.x) + h3y * (r2.x - r1.x);
        colp[c][1] = h1y * (r1.y - r0.y) + h3y * (r2.y - r1.y);
        colp[c][2] = h1y * (r1.z - r0.z) + h3y * (r2.z - r1.z);
        colp[c][3] = h1y * (r1.w - r0.w) + h3y * (r2.w - r1.w);
    }

    // NO __syncthreads(): each wave reads only its own LDS region; the
    // wave's own ds_write -> ds_read is ordered via lgkmcnt.

    // --- phase 2: per chunk, gather 3 taps/output from wave-private row ---
    float* orow = out + ((size_t)b * NGRID + (size_t)k) * NGRID;
    #pragma unroll
    for (int c = 0; c < 4; ++c) {
        const int s = c * 64 + lane;
        const float4 q4 = ((const float4*)xs)[s];
        float4 res;
        #pragma unroll
        for (int j = 0; j < 4; ++j) {
            const float q = ((const float*)&q4)[j];
            int Ix = (int)floorf(q);
            if (Ix < 0) Ix = 0;
            if (Ix > NGRID - 3) Ix = NGRID - 3;
            const float tx = q - (float)Ix;
            const float t2 = tx * tx;
            const float t3 = t2 * tx;
            const float w0 = 1.0f - tx - t2 + t3;
            const float w1 = tx + 2.0f * (t2 - t3);
            const float w2 = t3 - t2;
            const float c0 = crow[w][Ix];
            const float c1 = crow[w][Ix + 1];
            const float c2 = crow[w][Ix + 2];
            ((float*)&res)[j] = w0 * c0 + w1 * c1 + w2 * c2 + colp[c][j];
        }
        ((float4*)orow)[s] = res;   // normal store (nt reverted)
    }
}

extern "C" void kernel_launch(void* const* d_in, const int* in_sizes, int n_in,
                              void* d_out, int out_size, void* d_ws, size_t ws_size,
                              hipStream_t stream) {
    // inputs: 0=xaxis[N], 1=yaxis[N], 2=signal[B,N,N], 3=xs[N], 4=ys[N] (all f32)
    const float* signal = (const float*)d_in[2];
    const float* xs     = (const float*)d_in[3];
    const float* ys     = (const float*)d_in[4];
    float* out          = (float*)d_out;
    int*   perm         = (int*)d_ws;           // 4 KB of workspace

    build_perm<<<dim3(NGRID / 64), 64, 0, stream>>>(ys, perm);

    dim3 grid(NGRID * (BATCH / KB));    // 8192 blocks, 1D: (f&7)=XCD, (f>>3)=sorted pos
    hermite2d_fused<<<grid, 256, 0, stream>>>(signal, xs, ys, perm, out);
}

// Round 6
// 278.883 us; speedup vs baseline: 1.0657x; 1.0657x over previous
//
#include <hip/hip_runtime.h>

// CubicHermite2d: B=32, N=1024, axes are arange(N) => uniform knots, dx=1.
//
// out[b,k,p] = Hx(h0y*row_{Iy} + h2y*row_{Iy+1})(xs[p])
//            + h1y*(S[b,Iy+1,p]-S[b,Iy,p]) + h3y*(S[b,Iy+2,p]-S[b,Iy+1,p])
//
// Ledger: R0 baseline (this structure) kernel ~72.6us. R2/R4/R5/R6
// restructures (4-batch blocks, XCD pinning, nt-stores, b128 gather,
// zero-barrier, sorted k) all land 88-92us regardless of occupancy
// (36-67%), bank conflicts (3.1-7.4M) or FETCH (384->66MB). Conclusion:
// the KB=4 restructure itself cost ~16us; counters varied with no time
// effect. R7: EXACT R0 structure + the one proven-mechanism lever:
//   - sorted-k processing (R6 halved FETCH) but with CHUNKED mapping
//     sp=(x&7)*128+(x>>3): round-robin XCD dispatch then gives each XCD a
//     CONTIGUOUS run of sorted positions, so the 2-of-3 row overlap of
//     adjacent sorted k's is reused on the SAME XCD within ~2 block
//     generations -> L1/L2 hits (R6's %8 scatter put adjacent sorted k on
//     different XCDs -> only L3 caught the reuse).
//   - build_perm rebuilt: 1 block x 1024 thr, ys in LDS -> ~2us (was ~40).

#define NGRID 1024
#define BATCH 32

// ---- pre-kernel: perm = argsort(ys), brute-force rank, LDS-staged ----
__global__ __launch_bounds__(1024) void build_perm(
    const float* __restrict__ ys, int* __restrict__ perm)
{
    __shared__ float sy[NGRID];
    const int k = (int)threadIdx.x;
    const float v = ys[k];
    sy[k] = v;
    __syncthreads();
    int r = 0;
    #pragma unroll 8
    for (int j = 0; j < NGRID; ++j) {
        const float u = sy[j];                 // same addr all lanes: broadcast
        r += (u < v) || (u == v && j < k);     // stable total order -> bijection
    }
    perm[r] = k;
}

__global__ __launch_bounds__(256) void hermite2d_fused(
    const float* __restrict__ signal,   // [B, N, N]
    const float* __restrict__ xs,       // [N]
    const float* __restrict__ ys,       // [N]
    const int*   __restrict__ perm,     // [N] Iy-sorted k order
    float* __restrict__ out)            // [B, N(k), N(p)]
{
    // chunked sorted-position mapping: XCD (x&7) owns contiguous sorted
    // positions [ (x&7)*128, (x&7)*128+128 ), walked in order by x>>3.
    const unsigned x = blockIdx.x;
    const int sp = (int)(((x & 7u) << 7) | (x >> 3));   // bijective on [0,1024)
    const int k  = perm[sp];
    const int b  = blockIdx.y;
    const int t  = threadIdx.x;         // 256 threads; each owns columns 4t..4t+3

    __shared__ float crow[NGRID];       // h0y*row0 + h2y*row1

    // --- y-direction coefficients (block-uniform) ---
    const float qy = ys[k];
    int Iy = (int)floorf(qy);
    if (Iy < 0) Iy = 0;
    if (Iy > NGRID - 3) Iy = NGRID - 3;
    const float ty  = qy - (float)Iy;
    const float ty2 = ty * ty;
    const float ty3 = ty2 * ty;
    const float h0y = 1.0f - 3.0f * ty2 + 2.0f * ty3;
    const float h1y = ty - 2.0f * ty2 + ty3;
    const float h2y = 3.0f * ty2 - 2.0f * ty3;
    const float h3y = ty3 - ty2;

    // --- load 3 rows (float4 per thread), build combined row + column part ---
    const float4* src4 = (const float4*)(signal + ((size_t)b * NGRID + (size_t)Iy) * NGRID);
    const float4 r0 = src4[t];
    const float4 r1 = src4[t + NGRID / 4];
    const float4 r2 = src4[t + NGRID / 2];

    float4 c;
    c.x = h0y * r0.x + h2y * r1.x;
    c.y = h0y * r0.y + h2y * r1.y;
    c.z = h0y * r0.z + h2y * r1.z;
    c.w = h0y * r0.w + h2y * r1.w;
    ((float4*)crow)[t] = c;

    float colp[4];
    colp[0] = h1y * (r1.x - r0.x) + h3y * (r2.x - r1.x);
    colp[1] = h1y * (r1.y - r0.y) + h3y * (r2.y - r1.y);
    colp[2] = h1y * (r1.z - r0.z) + h3y * (r2.z - r1.z);
    colp[3] = h1y * (r1.w - r0.w) + h3y * (r2.w - r1.w);

    const float4 q4 = ((const float4*)xs)[t];
    const float qx[4] = { q4.x, q4.y, q4.z, q4.w };

    __syncthreads();

    // --- x-interp of the combined row + add column part ---
    float4 res;
    float* resp = (float*)&res;
    #pragma unroll
    for (int j = 0; j < 4; ++j) {
        const float q = qx[j];
        int Ix = (int)floorf(q);
        if (Ix < 0) Ix = 0;
        if (Ix > NGRID - 3) Ix = NGRID - 3;
        const float tx = q - (float)Ix;
        const float t2 = tx * tx;
        const float t3 = t2 * tx;
        const float w0 = 1.0f - tx - t2 + t3;
        const float w1 = tx + 2.0f * (t2 - t3);
        const float w2 = t3 - t2;
        const float c0 = crow[Ix];
        const float c1 = crow[Ix + 1];
        const float c2 = crow[Ix + 2];
        resp[j] = w0 * c0 + w1 * c1 + w2 * c2 + colp[j];
    }

    float4* orow4 = (float4*)(out + ((size_t)b * NGRID + (size_t)k) * NGRID);
    orow4[t] = res;
}

extern "C" void kernel_launch(void* const* d_in, const int* in_sizes, int n_in,
                              void* d_out, int out_size, void* d_ws, size_t ws_size,
                              hipStream_t stream) {
    // inputs: 0=xaxis[N], 1=yaxis[N], 2=signal[B,N,N], 3=xs[N], 4=ys[N] (all f32)
    const float* signal = (const float*)d_in[2];
    const float* xs     = (const float*)d_in[3];
    const float* ys     = (const float*)d_in[4];
    float* out          = (float*)d_out;
    int*   perm         = (int*)d_ws;           // 4 KB of workspace

    build_perm<<<dim3(1), 1024, 0, stream>>>(ys, perm);

    dim3 grid(NGRID, BATCH);
    hermite2d_fused<<<grid, 256, 0, stream>>>(signal, xs, ys, perm, out);
}

// Round 8
// 241.867 us; speedup vs baseline: 1.2288x; 1.1530x over previous
//
#include <hip/hip_runtime.h>

// CubicHermite2d: B=32, N=1024, axes are arange(N) => uniform knots, dx=1.
//
// out[b,k,p] = Hx(h0y*row_{Iy} + h2y*row_{Iy+1})(xs[p])
//            + h1y*(S[b,Iy+1,p]-S[b,Iy,p]) + h3y*(S[b,Iy+2,p]-S[b,Iy+1,p])
//
// Ledger R0-R7: kernel time invariant (72-92us) under fetch 384->66MB,
// conflicts 7.4M->3.1M, occupancy 36->67%, barrier removal, nt-stores,
// sorted-k locality. All mechanisms verified in counters; none moved time.
// Un-tried invariant: every variant had >=4-wave blocks in lockstep phases
// at ~16-21 waves/CU -> phase-1 VMEM latency and phase-2 LDS-pipe work
// never overlap across enough independent contexts.
// R8: ONE-WAVE BLOCKS. 64 threads per block, one (b,k) each, wave-private
// 4KB LDS row. LDS cap 160/4=40 -> wave cap 32 INDEPENDENT waves/CU, each
// at its own phase; single-wave s_barrier is ~free. No perm (R7's pre-
// kernel cost 40us for zero kernel gain -> dropped).
// (R9 = R8 resubmitted: container infra failure, kernel never ran.)

#define NGRID 1024
#define BATCH 32

__global__ __launch_bounds__(64) void hermite2d_fused(
    const float* __restrict__ signal,   // [B, N, N]
    const float* __restrict__ xs,       // [N]
    const float* __restrict__ ys,       // [N]
    float* __restrict__ out)            // [B, N(k), N(p)]
{
    const int k    = (int)blockIdx.x;   // y-query index
    const int b    = (int)blockIdx.y;   // batch
    const int lane = (int)threadIdx.x;  // 0..63; owns 16 columns (4 float4 slots)

    __shared__ float crow[NGRID];       // 4 KB, wave-private combined row

    // --- y-direction coefficients (uniform per block) ---
    const float qy = ys[k];
    int Iy = (int)floorf(qy);
    if (Iy < 0) Iy = 0;
    if (Iy > NGRID - 3) Iy = NGRID - 3;
    const float ty  = qy - (float)Iy;
    const float ty2 = ty * ty;
    const float ty3 = ty2 * ty;
    const float h0y = 1.0f - 3.0f * ty2 + 2.0f * ty3;
    const float h1y = ty - 2.0f * ty2 + ty3;
    const float h2y = 3.0f * ty2 - 2.0f * ty3;
    const float h3y = ty3 - ty2;

    const float4* src4 =
        (const float4*)(signal + ((size_t)b * NGRID + (size_t)Iy) * NGRID);

    // --- phase 1: 4 chunks; slot s=c*64+lane -> conflict-free b128 writes ---
    float colp[4][4];
    #pragma unroll
    for (int c = 0; c < 4; ++c) {
        const int s = c * 64 + lane;
        const float4 r0 = src4[s];
        const float4 r1 = src4[s + NGRID / 4];
        const float4 r2 = src4[s + NGRID / 2];

        float4 cc;
        cc.x = h0y * r0.x + h2y * r1.x;
        cc.y = h0y * r0.y + h2y * r1.y;
        cc.z = h0y * r0.z + h2y * r1.z;
        cc.w = h0y * r0.w + h2y * r1.w;
        ((float4*)crow)[s] = cc;

        colp[c][0] = h1y * (r1.x - r0.x) + h3y * (r2.x - r1.x);
        colp[c][1] = h1y * (r1.y - r0.y) + h3y * (r2.y - r1.y);
        colp[c][2] = h1y * (r1.z - r0.z) + h3y * (r2.z - r1.z);
        colp[c][3] = h1y * (r1.w - r0.w) + h3y * (r2.w - r1.w);
    }

    __syncthreads();    // single-wave barrier: effectively just the lgkmcnt drain

    // --- phase 2: 4 chunks; 3-tap gather per output from wave-private row ---
    float* orow = out + ((size_t)b * NGRID + (size_t)k) * NGRID;
    #pragma unroll
    for (int c = 0; c < 4; ++c) {
        const int s = c * 64 + lane;
        const float4 q4 = ((const float4*)xs)[s];
        float4 res;
        #pragma unroll
        for (int j = 0; j < 4; ++j) {
            const float q = ((const float*)&q4)[j];
            int Ix = (int)floorf(q);
            if (Ix < 0) Ix = 0;
            if (Ix > NGRID - 3) Ix = NGRID - 3;
            const float tx = q - (float)Ix;
            const float t2 = tx * tx;
            const float t3 = t2 * tx;
            const float w0 = 1.0f - tx - t2 + t3;
            const float w1 = tx + 2.0f * (t2 - t3);
            const float w2 = t3 - t2;
            const float c0 = crow[Ix];
            const float c1 = crow[Ix + 1];
            const float c2 = crow[Ix + 2];
            ((float*)&res)[j] = w0 * c0 + w1 * c1 + w2 * c2 + colp[c][j];
        }
        ((float4*)orow)[s] = res;
    }
}

extern "C" void kernel_launch(void* const* d_in, const int* in_sizes, int n_in,
                              void* d_out, int out_size, void* d_ws, size_t ws_size,
                              hipStream_t stream) {
    // inputs: 0=xaxis[N], 1=yaxis[N], 2=signal[B,N,N], 3=xs[N], 4=ys[N] (all f32)
    const float* signal = (const float*)d_in[2];
    const float* xs     = (const float*)d_in[3];
    const float* ys     = (const float*)d_in[4];
    float* out          = (float*)d_out;

    dim3 grid(NGRID, BATCH);            // 32768 one-wave blocks
    hermite2d_fused<<<grid, 64, 0, stream>>>(signal, xs, ys, out);
}